// Round 2
// baseline (1895.898 us; speedup 1.0000x reference)
//
#include <hip/hip_runtime.h>

// FlashAttentionWrapper: B=2, S=2048, D=2048, NH=32, HD=64, NKV=8, NREP=4,
// causal, RoPE theta=1e4. Dtype of inputs/output detected at runtime (bf16 or
// f32) — see detect_dtype. Internal intermediates always bf16.
// Workspace layout: [flag:4B pad to 1KB][kbuf 4MB][vbuf 4MB][abuf 16MB] = 24MB+1KB.
// Q-projection result lives in d_out (dead before O-proj overwrites it).

#define S_LEN 2048
#define D_MODEL 2048
#define NHEAD 32
#define HEAD_DIM 64
#define NKVH 8
#define M_ROWS 4096   // B*S

typedef __attribute__((ext_vector_type(4))) float f32x4;
typedef __attribute__((ext_vector_type(8))) short bf16x8;

#define MFMA16(a, b, c) __builtin_amdgcn_mfma_f32_16x16x32_bf16((a), (b), (c), 0, 0, 0)

static __device__ __forceinline__ unsigned short f2bf(float f) {
    union { float f; unsigned int i; } v; v.f = f;
    unsigned int x = v.i;
    unsigned int r = (x + 0x7fffu + ((x >> 16) & 1u)) >> 16;  // RNE
    return (unsigned short)r;
}

// ---------------------------------------------------------------------------
// Dtype detection: if d_in[0] is really f32 read as uint16, even-indexed
// elements are f32 low-mantissa bits -> uniform random "bf16 exponents";
// ~45% have exponent >= 141 (|x| >= 2^14) which never happens for N(0,1) bf16.
// ---------------------------------------------------------------------------
__global__ __launch_bounds__(256) void detect_dtype(const unsigned short* __restrict__ h,
                                                    int* __restrict__ flag) {
    __shared__ int cnt;
    if (threadIdx.x == 0) cnt = 0;
    __syncthreads();
    const unsigned short v = h[2 * threadIdx.x];
    const int e = (v >> 7) & 0xFF;
    if (e >= 0x8D) atomicAdd(&cnt, 1);
    __syncthreads();
    if (threadIdx.x == 0) *flag = (cnt >= 8) ? 1 : 0;
}

// Load 8 consecutive elements (element offset `off`) as bf16x8 from either a
// bf16 or an f32 buffer. f32p is block-uniform.
static __device__ __forceinline__ bf16x8 load_frag(bool f32p, const void* p, size_t off) {
    if (f32p) {
        const float* fp = (const float*)p + off;
        f32x4 x = *reinterpret_cast<const f32x4*>(fp);
        f32x4 y = *reinterpret_cast<const f32x4*>(fp + 4);
        bf16x8 r;
        r[0] = (short)f2bf(x[0]); r[1] = (short)f2bf(x[1]);
        r[2] = (short)f2bf(x[2]); r[3] = (short)f2bf(x[3]);
        r[4] = (short)f2bf(y[0]); r[5] = (short)f2bf(y[1]);
        r[6] = (short)f2bf(y[2]); r[7] = (short)f2bf(y[3]);
        return r;
    }
    return *reinterpret_cast<const bf16x8*>((const unsigned short*)p + off);
}

// ---------------------------------------------------------------------------
// GEMM: C[M,N] = A[M,2048] @ W[N,2048]^T  (fp32 acc). 64x64 tile per block,
// 4 waves x 16 rows. A/W may be bf16 or f32 (runtime flag); C is bf16 unless
// (finalout && f32 mode). Optional fused RoPE epilogue (rope != 0).
// ---------------------------------------------------------------------------
__global__ __launch_bounds__(256) void gemm_bt(const void* __restrict__ Ap,
                                               const void* __restrict__ Wp,
                                               void* __restrict__ Cp, int N,
                                               const int* __restrict__ flag,
                                               int a_input, int rope, int finalout) {
    const bool isf32 = (*flag != 0);
    const bool af32 = isf32 && (a_input != 0);
    const bool wf32 = isf32;                 // W is a model input in every call
    const bool of32 = isf32 && (finalout != 0);

    const int wave = threadIdx.x >> 6;
    const int lane = threadIdx.x & 63;
    const int l16  = lane & 15;
    const int quad = lane >> 4;
    const int m0 = blockIdx.x * 64 + wave * 16;
    const int n0 = blockIdx.y * 64;

    f32x4 acc[4];
#pragma unroll
    for (int i = 0; i < 4; ++i) acc[i] = (f32x4){0.f, 0.f, 0.f, 0.f};

    const size_t aoff = (size_t)(m0 + l16) * D_MODEL + quad * 8;
    size_t woff[4];
#pragma unroll
    for (int nt = 0; nt < 4; ++nt)
        woff[nt] = (size_t)(n0 + nt * 16 + l16) * D_MODEL + quad * 8;

    for (int k0 = 0; k0 < D_MODEL; k0 += 32) {
        bf16x8 a = load_frag(af32, Ap, aoff + k0);
#pragma unroll
        for (int nt = 0; nt < 4; ++nt) {
            bf16x8 b = load_frag(wf32, Wp, woff[nt] + k0);
            acc[nt] = MFMA16(a, b, acc[nt]);
        }
    }

    // epilogue: C/D layout row = quad*4 + r, col = nt*16 + l16
#pragma unroll
    for (int r = 0; r < 4; ++r) {
        const int m = m0 + quad * 4 + r;
        float vals[4];
#pragma unroll
        for (int nt = 0; nt < 4; ++nt) vals[nt] = acc[nt][r];
        float outv[4];
        if (rope) {
            const float sf = (float)(m & (S_LEN - 1));
#pragma unroll
            for (int nt = 0; nt < 4; ++nt) {
                const int d = nt * 16 + l16;             // n mod 64 (head dim)
                // inv_freq = 10000^(-(d&31)/32) = 2^(-(d&31)*log2(1e4)/32)
                const float inv = exp2f(-(float)(d & 31) * 0.4152410118609203f);
                const float th = sf * inv;
                float sn, cs;
                sincosf(th, &sn, &cs);
                const float part = vals[nt ^ 2];
                const float rot = (nt < 2) ? -part : part;  // d<32: -x2 ; d>=32: +x1
                outv[nt] = vals[nt] * cs + rot * sn;
            }
        } else {
#pragma unroll
            for (int nt = 0; nt < 4; ++nt) outv[nt] = vals[nt];
        }
        const size_t crow = (size_t)m * N + n0;
        if (of32) {
            float* cp = (float*)Cp + crow;
#pragma unroll
            for (int nt = 0; nt < 4; ++nt) cp[nt * 16 + l16] = outv[nt];
        } else {
            unsigned short* cp = (unsigned short*)Cp + crow;
#pragma unroll
            for (int nt = 0; nt < 4; ++nt) cp[nt * 16 + l16] = f2bf(outv[nt]);
        }
    }
}

// ---------------------------------------------------------------------------
// Flash attention, causal, GQA (4 q-heads per kv-head). Block = 4 waves;
// block handles (b, h, 64 q-rows); wave w owns 16 q-rows. 32-key tiles up to
// block-uniform bound qb*64+64. All Q/K/V/O buffers bf16 (internal).
// ---------------------------------------------------------------------------
__global__ __launch_bounds__(256) void attn_kernel(const unsigned short* __restrict__ Q,
                                                   const unsigned short* __restrict__ Kb,
                                                   const unsigned short* __restrict__ Vb,
                                                   unsigned short* __restrict__ O) {
    __shared__ unsigned short lp[4][16][32];   // per-wave P tile (16 q x 32 k)

    const int wave = threadIdx.x >> 6;
    const int lane = threadIdx.x & 63;
    const int l16  = lane & 15;
    const int quad = lane >> 4;

    const int bid = blockIdx.x;
    const int qb  = bid & 31;          // S/64 q-tiles
    const int h   = (bid >> 5) & 31;
    const int b   = bid >> 10;
    const int kvh = h >> 2;            // NREP = 4
    const int q0  = qb * 64 + wave * 16;

    const unsigned short* qbase = Q + (size_t)b * S_LEN * D_MODEL + h * HEAD_DIM;
    const unsigned short* kbase = Kb + (size_t)b * S_LEN * (NKVH * HEAD_DIM) + kvh * HEAD_DIM;
    const unsigned short* vbase = Vb + (size_t)b * S_LEN * (NKVH * HEAD_DIM) + kvh * HEAD_DIM;

    // Q fragments (A-operand: m=l16, k=quad*8+j), two K=32 halves of HD=64
    bf16x8 aq0 = *reinterpret_cast<const bf16x8*>(qbase + (size_t)(q0 + l16) * D_MODEL + quad * 8);
    bf16x8 aq1 = *reinterpret_cast<const bf16x8*>(qbase + (size_t)(q0 + l16) * D_MODEL + 32 + quad * 8);

    f32x4 o[4];
#pragma unroll
    for (int i = 0; i < 4; ++i) o[i] = (f32x4){0.f, 0.f, 0.f, 0.f};
    float mrow[4], lrow[4];
#pragma unroll
    for (int r = 0; r < 4; ++r) { mrow[r] = -3.0e38f; lrow[r] = 0.f; }

    const int kv_hi = qb * 64 + 64;    // block-uniform
    for (int k0 = 0; k0 < kv_hi; k0 += 32) {
        // ---- scores: 16x32 via two 16x16 C-tiles ----
        f32x4 sc[2];
#pragma unroll
        for (int t = 0; t < 2; ++t) {
            const unsigned short* krow = kbase + (size_t)(k0 + t * 16 + l16) * (NKVH * HEAD_DIM);
            bf16x8 b0 = *reinterpret_cast<const bf16x8*>(krow + quad * 8);
            bf16x8 b1 = *reinterpret_cast<const bf16x8*>(krow + 32 + quad * 8);
            f32x4 c = (f32x4){0.f, 0.f, 0.f, 0.f};
            c = MFMA16(aq0, b0, c);
            c = MFMA16(aq1, b1, c);
            sc[t] = c;
        }

        // ---- scale + causal mask + online softmax ----
        float alpha[4], p0v[4], p1v[4];
#pragma unroll
        for (int r = 0; r < 4; ++r) {
            const int qi = q0 + quad * 4 + r;
            float s0 = sc[0][r] * 0.125f;
            float s1 = sc[1][r] * 0.125f;
            if (k0 + l16 > qi)       s0 = -1.0e30f;
            if (k0 + 16 + l16 > qi)  s1 = -1.0e30f;
            float mt = fmaxf(s0, s1);
#pragma unroll
            for (int off = 1; off < 16; off <<= 1) mt = fmaxf(mt, __shfl_xor(mt, off, 64));
            const float mn = fmaxf(mrow[r], mt);
            const float al = __expf(mrow[r] - mn);
            const float p0 = __expf(s0 - mn);
            const float p1 = __expf(s1 - mn);
            float rs = p0 + p1;
#pragma unroll
            for (int off = 1; off < 16; off <<= 1) rs += __shfl_xor(rs, off, 64);
            lrow[r] = lrow[r] * al + rs;
            mrow[r] = mn;
            alpha[r] = al;
            p0v[r] = p0; p1v[r] = p1;
        }
#pragma unroll
        for (int nt = 0; nt < 4; ++nt)
#pragma unroll
            for (int r = 0; r < 4; ++r) o[nt][r] *= alpha[r];

        // ---- P: C-layout -> A-layout via LDS (per-wave slice) ----
        __syncthreads();
#pragma unroll
        for (int r = 0; r < 4; ++r) {
            lp[wave][quad * 4 + r][l16]      = f2bf(p0v[r]);
            lp[wave][quad * 4 + r][16 + l16] = f2bf(p1v[r]);
        }
        __syncthreads();
        bf16x8 ap = *reinterpret_cast<const bf16x8*>(&lp[wave][l16][quad * 8]);

        // ---- PV: o[nt] += P(16x32) @ V(32x16) ----
#pragma unroll
        for (int nt = 0; nt < 4; ++nt) {
            const unsigned short* vcol = vbase + nt * 16 + l16 + (size_t)(k0 + quad * 8) * (NKVH * HEAD_DIM);
            bf16x8 bv;
#pragma unroll
            for (int j = 0; j < 8; ++j) bv[j] = (short)vcol[(size_t)j * (NKVH * HEAD_DIM)];
            o[nt] = MFMA16(ap, bv, o[nt]);
        }
    }

    // ---- normalize + store (bf16) ----
    unsigned short* obase = O + (size_t)b * S_LEN * D_MODEL + h * HEAD_DIM;
#pragma unroll
    for (int r = 0; r < 4; ++r) {
        const float inv_l = 1.0f / lrow[r];
        unsigned short* orow = obase + (size_t)(q0 + quad * 4 + r) * D_MODEL;
#pragma unroll
        for (int nt = 0; nt < 4; ++nt)
            orow[nt * 16 + l16] = f2bf(o[nt][r] * inv_l);
    }
}

extern "C" void kernel_launch(void* const* d_in, const int* in_sizes, int n_in,
                              void* d_out, int out_size, void* d_ws, size_t ws_size,
                              hipStream_t stream) {
    const void* hidden = d_in[0];
    const void* Wq = d_in[1];
    const void* Wk = d_in[2];
    const void* Wv = d_in[3];
    const void* Wo = d_in[4];
    // d_in[5] = attention_mask: pure causal -1e9 -> implemented directly.

    char* ws = (char*)d_ws;
    int* flag = (int*)ws;                                             // 4B
    unsigned short* kbuf = (unsigned short*)(ws + 1024);              // 4096x512 bf16 (4MB)
    unsigned short* vbuf = (unsigned short*)(ws + 1024 + (4u << 20)); // 4MB
    unsigned short* abuf = (unsigned short*)(ws + 1024 + (8u << 20)); // 4096x2048 bf16 (16MB)
    unsigned short* qbuf = (unsigned short*)d_out;                    // Q lives in d_out (dead before O-proj)

    dim3 blk(256);
    detect_dtype<<<1, blk, 0, stream>>>((const unsigned short*)hidden, flag);
    gemm_bt<<<dim3(M_ROWS / 64, D_MODEL / 64), blk, 0, stream>>>(hidden, Wq, qbuf, D_MODEL, flag, 1, 1, 0);
    gemm_bt<<<dim3(M_ROWS / 64, (NKVH * HEAD_DIM) / 64), blk, 0, stream>>>(hidden, Wk, kbuf, NKVH * HEAD_DIM, flag, 1, 1, 0);
    gemm_bt<<<dim3(M_ROWS / 64, (NKVH * HEAD_DIM) / 64), blk, 0, stream>>>(hidden, Wv, vbuf, NKVH * HEAD_DIM, flag, 1, 0, 0);
    attn_kernel<<<dim3(2 * NHEAD * (S_LEN / 64)), blk, 0, stream>>>(qbuf, kbuf, vbuf, abuf);
    gemm_bt<<<dim3(M_ROWS / 64, D_MODEL / 64), blk, 0, stream>>>(abuf, Wo, d_out, D_MODEL, flag, 0, 0, 1);
}